// Round 10
// baseline (1184.103 us; speedup 1.0000x reference)
//
#include <hip/hip_runtime.h>
#include <stdint.h>
#include <math.h>

#define T_SIM 500
#define NB    64
#define NIN   1024
#define NHID  1024
#define NOUT  10
#define KSRM  77     // SRM kernel taps 0..76 (srm[0] == 0)
#define CHUNK 32     // batches per chunk for layer-1 pipeline
#define TT5   12     // t-tile in fused psp+spike kernel
#define NT5   42     // ceil(500/12); last tile tv=8
#define RING5 128    // pow2 ring; needed span 76+2*12=100 <= 128

// Reference builds kernels in python f64 then rounds to fp32; we reproduce the
// exact fp32 tap values and do all accumulation in f64 (verified: absmax 0).
__device__ __forceinline__ double srm_tap(int k) {
  double u = (double)k / 10.0;
  double v = u * exp(1.0 - u);
  return (double)(float)v;
}
__device__ __forceinline__ double ref_tap(int j) {
  double v = (-20.0 * (double)j) * exp(1.0 - (double)j);
  return (double)(float)v;
}

// ---------------------------------------------------------------------------
// K0: pack binary input spikes x[b][i][t] (fp32 0/1) -> bits [b][t][16 x u64]
__global__ __launch_bounds__(64)
void k_pack(const float* __restrict__ x, unsigned long long* __restrict__ bits) {
  const int b = blockIdx.x, ig = blockIdx.y, tc = blockIdx.z;
  const int lane = threadIdx.x;
  const float* xr = x + ((size_t)b * NIN + ig * 64 + lane) * T_SIM;
  const int t0 = tc * 100;
  for (int t = t0; t < t0 + 100; t += 4) {
    const float4 v = *(const float4*)(xr + t);
    unsigned long long m0 = __ballot(v.x > 0.5f);
    unsigned long long m1 = __ballot(v.y > 0.5f);
    unsigned long long m2 = __ballot(v.z > 0.5f);
    unsigned long long m3 = __ballot(v.w > 0.5f);
    if (lane == 0) {
      unsigned long long* w = bits + (size_t)(b * T_SIM + t) * 16 + ig;
      w[0] = m0; w[16] = m1; w[32] = m2; w[48] = m3;
    }
  }
}

// ---------------------------------------------------------------------------
// K0b: W1[o][i] -> W1T[i][o] fp32, tiled 64x64 through LDS.
__global__ __launch_bounds__(256)
void k_transpose(const float* __restrict__ W1, float* __restrict__ W1T) {
  __shared__ float tile[64][65];
  const int bo = blockIdx.x * 64, bi = blockIdx.y * 64;
  for (int k = threadIdx.x; k < 4096; k += 256) {
    int r = k >> 6, c = k & 63;
    tile[r][c] = W1[(size_t)(bo + r) * NIN + bi + c];
  }
  __syncthreads();
  for (int k = threadIdx.x; k < 4096; k += 256) {
    int r = k >> 6, c = k & 63;
    W1T[(size_t)(bi + r) * NHID + bo + c] = tile[c][r];
  }
}

// ---------------------------------------------------------------------------
// K1: dense1 v4 — LDS-staged W1T with column-tile reuse.
// Block = 64 columns x 128-o slice, 512 threads (4 col-groups x 128 o).
// 16 i-tiles: stage W1T[64 i][128 o] (32 KB) in LDS, each thread accumulates
// its 16 columns' active rows from LDS (wave-uniform masks, no divergence).
// Global W1T traffic: 3.28 GB -> 1.0 GB/launch; blockIdx.x = ct*8+ot pins
// each 128-o slice (512 KB) to one XCD L2 via round-robin dispatch.
// Per-(col,o) sum: single f64 acc, i ascending == R2/R3 order (absmax 0).
// LDS: 64*128*4 + 64*32*4 = 40,960 B. grid (250*8), block 512.
__global__ __launch_bounds__(512)
void k_dense1(const uint32_t* __restrict__ bits, const float* __restrict__ W1T,
              double* __restrict__ a1c, int col_base) {
  __shared__ float Wl[64][128];     // 32 KB  [i_local][o_local]
  __shared__ uint32_t Lm[64][32];   // 8 KB   [col_local][mask word]
  const int ct = blockIdx.x >> 3;         // column tile 0..249
  const int ot = blockIdx.x & 7;          // o tile 0..7
  const int tid = threadIdx.x;
  const int o_l = tid & 127;              // o within slice
  const int cg  = tid >> 7;               // col group 0..3 (16 cols each)
  const int col0 = ct * 64;               // local col base (within chunk)
  const int o0 = ot * 128;

  // stage all 64 columns' masks once (2048 u32, coalesced)
  for (int idx = tid; idx < 64 * 32; idx += 512) {
    const int c = idx >> 5, w = idx & 31;
    Lm[c][w] = bits[(size_t)(col_base + col0 + c) * 32 + w];
  }

  double acc[16];
#pragma unroll
  for (int c = 0; c < 16; ++c) acc[c] = 0.0;

  for (int it = 0; it < 16; ++it) {
    __syncthreads();   // previous tile fully consumed (also covers Lm on it=0)
    // ---- stage W1T[it*64 .. +63][o0 .. +127] into LDS ----
#pragma unroll
    for (int v = 0; v < 4; ++v) {
      const int idx = v * 512 + tid;      // float4 units, 0..2047
      const int row = idx >> 5, c4 = idx & 31;
      *(float4*)&Wl[row][c4 * 4] =
          *(const float4*)(W1T + (size_t)(it * 64 + row) * NHID + o0 + c4 * 4);
    }
    __syncthreads();
    // ---- accumulate: 16 cols/thread, masks wave-uniform ----
#pragma unroll
    for (int c = 0; c < 16; ++c) {
      uint32_t m0 = Lm[cg * 16 + c][2 * it];
      uint32_t m1 = Lm[cg * 16 + c][2 * it + 1];
      while (m0) {
        const int j = __ffs(m0) - 1; m0 &= m0 - 1;
        acc[c] += (double)Wl[j][o_l];
      }
      while (m1) {
        const int j = __ffs(m1) - 1; m1 &= m1 - 1;
        acc[c] += (double)Wl[32 + j][o_l];
      }
    }
  }
  // ---- write out: a1c[col][o] f64, nt stores ----
#pragma unroll
  for (int c = 0; c < 16; ++c) {
    const int col = col0 + cg * 16 + c;
    __builtin_nontemporal_store(acc[c], a1c + (size_t)col * NHID + o0 + o_l);
  }
}

// ---------------------------------------------------------------------------
// K2: FUSED psp1 + spike1 (exact R7 version, 192 us proven). 448 thr: 384 FIR
// (4 tap-groups x 3 t-quads x 32 n, TT=12) + scan wave overlapping tile k-1.
// Ring 128 rows (pow2). One barrier per tile. grid (32, CHUNK).
// LDS: 128*32*8 + 2*4*12*32*8 + 80*8 = 57,984 B -> 2 blocks/CU.
__global__ __launch_bounds__(448)
void k_ps1(const double* __restrict__ a1c, uint32_t* __restrict__ s1w,
           int b_base) {
  __shared__ double S[RING5 * 32];
  __shared__ double Yp[2][4][TT5 * 32];
  __shared__ double TB[80];     // srm[0..76], zero-padded to 80
  const int ng = blockIdx.x, b_loc = blockIdx.y;
  const int tid = threadIdx.x;
  const double* __restrict__ abase = a1c + (size_t)b_loc * T_SIM * NHID + ng * 32;
  uint32_t* __restrict__ sbase = s1w + (size_t)(b_base + b_loc) * T_SIM * 32 + ng;

  if (tid < 80) TB[tid] = (tid <= 76) ? srm_tap(tid) : 0.0;
  for (int i = tid; i < RING5 * 32; i += 448) S[i] = 0.0;
  __syncthreads();
  for (int id = tid; id < TT5 * 32; id += 448) {   // tile 0 -> slots 0..11
    const int r = id >> 5, nn = id & 31;
    S[r * 32 + nn] = abase[(size_t)r * NHID + nn];
  }

  const bool isFIR = (tid < 384);
  const int g   = tid / 96;          // tap group 0..3 (FIR threads)
  const int rem = tid - g * 96;
  const int q   = rem >> 5;          // t-quad 0..2
  const int n   = rem & 31;          // neuron
  double tap[20];
  __syncthreads();                   // TB + tile0 visible
  if (isFIR) {
#pragma unroll
    for (int j = 0; j < 20; ++j) tap[j] = TB[20 * g + j];
  }
  double refk[11];
#pragma unroll
  for (int j = 1; j <= 10; ++j) refk[j] = ref_tap(j);
  uint32_t smask = 0;

  for (int k = 0; k < NT5; ++k) {
    const int t0 = k * TT5;
    const int tv = (T_SIM - t0 < TT5) ? (T_SIM - t0) : TT5;
    const int t0n = t0 + TT5;
    const int tvn = (t0n >= T_SIM) ? 0 : ((T_SIM - t0n < TT5) ? (T_SIM - t0n) : TT5);
    if (isFIR) {
      // ---- prefetch 1 element of tile k+1 (completes under the FIR) ----
      double pf = 0.0;
      const int pr = tid >> 5, pn = tid & 31;
      const bool hasPf = (tid < tvn * 32);
      if (hasPf) pf = abase[(size_t)(t0n + pr) * NHID + pn];
      // ---- partial FIR: outputs tb..tb+3, taps 20g..20g+19 ----
      const int tb = t0 + q * 4;
      int slot = (tb - 20 * g - 19 + 1024) & (RING5 - 1);
      double a0 = 0, a1 = 0, a2 = 0, a3 = 0;
#pragma unroll
      for (int s = 0; s < 23; ++s) {
        const double v = S[slot * 32 + n];
        slot = (slot + 1) & (RING5 - 1);
        if (s <= 19)           a0 += tap[19 - s] * v;
        if (s >= 1 && s <= 20) a1 += tap[20 - s] * v;
        if (s >= 2 && s <= 21) a2 += tap[21 - s] * v;
        if (s >= 3)            a3 += tap[22 - s] * v;
      }
      double* Yk = Yp[k & 1][g];
      const int tl = q * 4;
      if (tl + 0 < tv) Yk[(tl + 0) * 32 + n] = a0;
      if (tl + 1 < tv) Yk[(tl + 1) * 32 + n] = a1;
      if (tl + 2 < tv) Yk[(tl + 2) * 32 + n] = a2;
      if (tl + 3 < tv) Yk[(tl + 3) * 32 + n] = a3;
      // ---- write prefetched row into ring (slots disjoint from window k) ----
      if (hasPf) S[((t0n + pr) & (RING5 - 1)) * 32 + pn] = pf;
    } else if (k > 0) {
      // ---- scan wave: refractory scan of tile k-1 (tv always 12 there) ----
      const int lane = tid - 384;
      if (lane < 32) {
        const int t0p = t0 - TT5;
        const double* Y0 = Yp[(k - 1) & 1][0];
        const double* Y1 = Yp[(k - 1) & 1][1];
        const double* Y2 = Yp[(k - 1) & 1][2];
        const double* Y3 = Yp[(k - 1) & 1][3];
        for (int gg = 0; gg < TT5; ++gg) {
          double u = (Y0[gg * 32 + lane] + Y1[gg * 32 + lane]) +
                     (Y2[gg * 32 + lane] + Y3[gg * 32 + lane]);
#pragma unroll
          for (int j = 10; j >= 1; --j)
            u += refk[j] * (double)((smask >> (j - 1)) & 1u);
          const bool sp = (u >= 10.0);
          smask = (smask << 1) | (sp ? 1u : 0u);
          const unsigned long long bm = __ballot(sp);
          if (lane == 0) sbase[(size_t)(t0p + gg) * 32] = (uint32_t)bm;
        }
      }
    }
    __syncthreads();
  }
  // ---- epilogue: scan last tile (t0p = 492, tv = 8) ----
  if (!isFIR) {
    const int lane = tid - 384;
    if (lane < 32) {
      const int t0p = (NT5 - 1) * TT5;
      const int tvp = T_SIM - t0p;
      const double* Y0 = Yp[(NT5 - 1) & 1][0];
      const double* Y1 = Yp[(NT5 - 1) & 1][1];
      const double* Y2 = Yp[(NT5 - 1) & 1][2];
      const double* Y3 = Yp[(NT5 - 1) & 1][3];
      for (int gg = 0; gg < tvp; ++gg) {
        double u = (Y0[gg * 32 + lane] + Y1[gg * 32 + lane]) +
                   (Y2[gg * 32 + lane] + Y3[gg * 32 + lane]);
#pragma unroll
        for (int j = 10; j >= 1; --j)
          u += refk[j] * (double)((smask >> (j - 1)) & 1u);
        const bool sp = (u >= 10.0);
        smask = (smask << 1) | (sp ? 1u : 0u);
        const unsigned long long bm = __ballot(sp);
        if (lane == 0) sbase[(size_t)(t0p + gg) * 32] = (uint32_t)bm;
      }
    }
  }
}

// ---------------------------------------------------------------------------
// K3: dense2 sparse gather from s1 u32 masks, W2 fp32 in LDS, f64 acc.
__global__ __launch_bounds__(256)
void k_dense2(const uint32_t* __restrict__ s1w,
              const float* __restrict__ W2, double* __restrict__ a2) {
  __shared__ float w2t[NHID * NOUT];  // 40 KB, [i][o]
  for (int k = threadIdx.x; k < NHID * NOUT; k += 256) {
    const int o = k >> 10, i = k & 1023;
    w2t[i * NOUT + o] = W2[k];
  }
  __syncthreads();
  const int col = blockIdx.x * 256 + threadIdx.x;  // 0..31999
  double acc[NOUT];
#pragma unroll
  for (int o = 0; o < NOUT; ++o) acc[o] = 0.0;
  const uint32_t* w = s1w + (size_t)col * 32;
  for (int wi = 0; wi < 32; ++wi) {
    uint32_t m = w[wi];
    const int ibase = wi * 32;
    while (m) {
      const int j = __ffs(m) - 1;
      m &= m - 1;
      const float* row = &w2t[(ibase + j) * NOUT];
#pragma unroll
      for (int o = 0; o < NOUT; ++o) acc[o] += (double)row[o];
    }
  }
  double* outp = a2 + (size_t)col * NOUT;
#pragma unroll
  for (int o = 0; o < NOUT; ++o) outp[o] = acc[o];
}

// ---------------------------------------------------------------------------
// K4: FUSED psp2 + spike2, one block per batch; whole [500][10] in LDS.
__global__ __launch_bounds__(256)
void k_l2(const double* __restrict__ a2, float* __restrict__ out) {
  __shared__ double S[T_SIM * NOUT];
  __shared__ double Y[T_SIM * NOUT];
  __shared__ double srm[KSRM];
  const int b = blockIdx.x, tid = threadIdx.x;
  if (tid < KSRM) srm[tid] = srm_tap(tid);
  for (int i = tid; i < T_SIM * NOUT; i += 256)
    S[i] = a2[(size_t)b * T_SIM * NOUT + i];
  __syncthreads();
  for (int i = tid; i < T_SIM * NOUT; i += 256) {
    const int t = i / 10, o = i - t * 10;
    const int kmax = (t < KSRM - 1) ? t : (KSRM - 1);
    double acc = 0.0;
    for (int k = 0; k <= kmax; ++k)
      acc += srm[k] * S[(t - k) * 10 + o];
    Y[i] = acc;
  }
  __syncthreads();
  if (tid < NOUT) {
    double refk[11];
#pragma unroll
    for (int j = 1; j <= 10; ++j) refk[j] = ref_tap(j);
    uint32_t smask = 0;
    float* op = out + ((size_t)b * NOUT + tid) * T_SIM;
    for (int t = 0; t < T_SIM; ++t) {
      double u = Y[t * 10 + tid];
#pragma unroll
      for (int j = 10; j >= 1; --j)
        u += refk[j] * (double)((smask >> (j - 1)) & 1u);
      const bool sp = (u >= 10.0);
      smask = (smask << 1) | (sp ? 1u : 0u);
      op[t] = sp ? 1.0f : 0.0f;
    }
  }
}

// ---------------------------------------------------------------------------
extern "C" void kernel_launch(void* const* d_in, const int* in_sizes, int n_in,
                              void* d_out, int out_size, void* d_ws, size_t ws_size,
                              hipStream_t stream) {
  const float* x  = (const float*)d_in[0];   // [64][1024][500]
  const float* W1 = (const float*)d_in[1];   // [1024][1024]
  const float* W2 = (const float*)d_in[2];   // [10][1024]
  float* out = (float*)d_out;                // [64][10][500]

  char* ws = (char*)d_ws;
  unsigned long long* bits1 = (unsigned long long*)(ws);   // 4,096,000
  float*  W1T = (float*) (ws + 4096000);                   // 4,194,304
  double* a1c = (double*)(ws + 8290304);                   // 131,072,000 (CHUNK=32)
  uint32_t* s1w = (uint32_t*)(ws + 139362304);             // 4,096,000
  double* a2  = (double*)(ws + 143458304);                 // 2,560,000
  // total ws use: 146,018,304 B

  hipLaunchKernelGGL(k_pack, dim3(NB, 16, 5), dim3(64), 0, stream, x, bits1);
  hipLaunchKernelGGL(k_transpose, dim3(16, 16), dim3(256), 0, stream, W1, W1T);

  for (int bc = 0; bc < NB; bc += CHUNK) {
    hipLaunchKernelGGL(k_dense1, dim3(250 * 8), dim3(512), 0, stream,
                       (const uint32_t*)bits1, W1T, a1c, bc * T_SIM);
    hipLaunchKernelGGL(k_ps1, dim3(32, CHUNK), dim3(448), 0, stream,
                       a1c, s1w, bc);
  }

  hipLaunchKernelGGL(k_dense2, dim3(125), dim3(256), 0, stream, s1w, W2, a2);
  hipLaunchKernelGGL(k_l2, dim3(NB), dim3(256), 0, stream, a2, out);
}

// Round 11
// 997.495 us; speedup vs baseline: 1.1871x; 1.1871x over previous
//
#include <hip/hip_runtime.h>
#include <stdint.h>
#include <math.h>

#define T_SIM 500
#define NB    64
#define NIN   1024
#define NHID  1024
#define NOUT  10
#define KSRM  77     // SRM kernel taps 0..76 (srm[0] == 0)
#define CHUNK 32     // batches per chunk for layer-1 pipeline
#define TT5   12     // t-tile in fused psp+spike kernel
#define NT5   42     // ceil(500/12); last tile tv=8
#define RING5 128    // pow2 ring; needed span 76+2*12=100 <= 128

// Reference builds kernels in python f64 then rounds to fp32; we reproduce the
// exact fp32 tap values and do all accumulation in f64 (verified: absmax 0).
__device__ __forceinline__ double srm_tap(int k) {
  double u = (double)k / 10.0;
  double v = u * exp(1.0 - u);
  return (double)(float)v;
}
__device__ __forceinline__ double ref_tap(int j) {
  double v = (-20.0 * (double)j) * exp(1.0 - (double)j);
  return (double)(float)v;
}

// ---------------------------------------------------------------------------
// K0: pack binary input spikes x[b][i][t] (fp32 0/1) -> bits [b][t][16 x u64]
__global__ __launch_bounds__(64)
void k_pack(const float* __restrict__ x, unsigned long long* __restrict__ bits) {
  const int b = blockIdx.x, ig = blockIdx.y, tc = blockIdx.z;
  const int lane = threadIdx.x;
  const float* xr = x + ((size_t)b * NIN + ig * 64 + lane) * T_SIM;
  const int t0 = tc * 100;
  for (int t = t0; t < t0 + 100; t += 4) {
    const float4 v = *(const float4*)(xr + t);
    unsigned long long m0 = __ballot(v.x > 0.5f);
    unsigned long long m1 = __ballot(v.y > 0.5f);
    unsigned long long m2 = __ballot(v.z > 0.5f);
    unsigned long long m3 = __ballot(v.w > 0.5f);
    if (lane == 0) {
      unsigned long long* w = bits + (size_t)(b * T_SIM + t) * 16 + ig;
      w[0] = m0; w[16] = m1; w[32] = m2; w[48] = m3;
    }
  }
}

// ---------------------------------------------------------------------------
// K0b: W1[o][i] -> W1T[i][o] fp32, tiled 64x64 through LDS.
__global__ __launch_bounds__(256)
void k_transpose(const float* __restrict__ W1, float* __restrict__ W1T) {
  __shared__ float tile[64][65];
  const int bo = blockIdx.x * 64, bi = blockIdx.y * 64;
  for (int k = threadIdx.x; k < 4096; k += 256) {
    int r = k >> 6, c = k & 63;
    tile[r][c] = W1[(size_t)(bo + r) * NIN + bi + c];
  }
  __syncthreads();
  for (int k = threadIdx.x; k < 4096; k += 256) {
    int r = k >> 6, c = k & 63;
    W1T[(size_t)(bi + r) * NHID + bo + c] = tile[c][r];
  }
}

// ---------------------------------------------------------------------------
// K1: dense1 v5 — LDS-staged W1T, wave-uniform masks, 4 outputs per element.
// Block = 64 cols x 256-o slice, 512 thr; thread = 8 cols x 4 o (ow=tid&63 so
// a wave's 64 lanes share one col-group: masks wave-uniform, no divergence).
// Per active element: 1 ds_read_b128 (16B/lane contiguous, conflict-free) +
// 4 f64 adds, serving 256 outputs per wave-element. 16 i-tiles of 64x256 f32.
// Per-(col,o) sum: single f64 acc, i ascending == R10 order (absmax 0).
// LDS: 64*256*4 + 64*32*4 = 73,728 B -> 2 blocks/CU. grid (250*4), block 512.
__global__ __launch_bounds__(512)
void k_dense1(const uint32_t* __restrict__ bits, const float* __restrict__ W1T,
              double* __restrict__ a1c, int col_base) {
  __shared__ float Wl[64][256];     // 64 KB  [i_local][o_local]
  __shared__ uint32_t Lm[64][32];   // 8 KB   [col_local][mask word]
  const int ct = blockIdx.x >> 2;         // column tile 0..249
  const int ot = blockIdx.x & 3;          // o slice 0..3
  const int tid = threadIdx.x;
  const int ow = tid & 63;                // o-quad index within slice
  const int cg = tid >> 6;                // col group 0..7 (8 cols each)
  const int col0 = ct * 64;               // local col base (within chunk)
  const int o0 = ot * 256;

  // stage all 64 columns' masks once (2048 u32, coalesced)
  for (int idx = tid; idx < 64 * 32; idx += 512) {
    const int c = idx >> 5, w = idx & 31;
    Lm[c][w] = bits[(size_t)(col_base + col0 + c) * 32 + w];
  }

  double acc[8][4];
#pragma unroll
  for (int c = 0; c < 8; ++c)
#pragma unroll
    for (int u = 0; u < 4; ++u) acc[c][u] = 0.0;

  for (int it = 0; it < 16; ++it) {
    __syncthreads();   // previous tile fully consumed (also covers Lm on it=0)
    // ---- stage W1T[it*64 .. +63][o0 .. +255] into LDS (4096 float4) ----
#pragma unroll
    for (int v = 0; v < 8; ++v) {
      const int idx = v * 512 + tid;      // float4 units, 0..4095
      const int row = idx >> 6, c4 = idx & 63;
      *(float4*)&Wl[row][c4 * 4] =
          *(const float4*)(W1T + (size_t)(it * 64 + row) * NHID + o0 + c4 * 4);
    }
    __syncthreads();
    // ---- accumulate: 8 cols/thread, masks wave-uniform, b128 reads ----
#pragma unroll
    for (int c = 0; c < 8; ++c) {
      uint32_t m0 = Lm[cg * 8 + c][2 * it];
      uint32_t m1 = Lm[cg * 8 + c][2 * it + 1];
      while (m0) {
        const int j = __ffs(m0) - 1; m0 &= m0 - 1;
        const float4 wv = *(const float4*)&Wl[j][ow * 4];
        acc[c][0] += (double)wv.x; acc[c][1] += (double)wv.y;
        acc[c][2] += (double)wv.z; acc[c][3] += (double)wv.w;
      }
      while (m1) {
        const int j = __ffs(m1) - 1; m1 &= m1 - 1;
        const float4 wv = *(const float4*)&Wl[32 + j][ow * 4];
        acc[c][0] += (double)wv.x; acc[c][1] += (double)wv.y;
        acc[c][2] += (double)wv.z; acc[c][3] += (double)wv.w;
      }
    }
  }
  // ---- write out: a1c[col][o] f64 (plain stores -> L2 for ps1) ----
#pragma unroll
  for (int c = 0; c < 8; ++c) {
    const int col = col0 + cg * 8 + c;
    double* dst = a1c + (size_t)col * NHID + o0 + ow * 4;
    dst[0] = acc[c][0]; dst[1] = acc[c][1];
    dst[2] = acc[c][2]; dst[3] = acc[c][3];
  }
}

// ---------------------------------------------------------------------------
// K2: FUSED psp1 + spike1 (exact R7 version, 192 us proven). 448 thr: 384 FIR
// (4 tap-groups x 3 t-quads x 32 n, TT=12) + scan wave overlapping tile k-1.
// Ring 128 rows (pow2). One barrier per tile. grid (32, CHUNK).
// LDS: 128*32*8 + 2*4*12*32*8 + 80*8 = 57,984 B -> 2 blocks/CU.
__global__ __launch_bounds__(448)
void k_ps1(const double* __restrict__ a1c, uint32_t* __restrict__ s1w,
           int b_base) {
  __shared__ double S[RING5 * 32];
  __shared__ double Yp[2][4][TT5 * 32];
  __shared__ double TB[80];     // srm[0..76], zero-padded to 80
  const int ng = blockIdx.x, b_loc = blockIdx.y;
  const int tid = threadIdx.x;
  const double* __restrict__ abase = a1c + (size_t)b_loc * T_SIM * NHID + ng * 32;
  uint32_t* __restrict__ sbase = s1w + (size_t)(b_base + b_loc) * T_SIM * 32 + ng;

  if (tid < 80) TB[tid] = (tid <= 76) ? srm_tap(tid) : 0.0;
  for (int i = tid; i < RING5 * 32; i += 448) S[i] = 0.0;
  __syncthreads();
  for (int id = tid; id < TT5 * 32; id += 448) {   // tile 0 -> slots 0..11
    const int r = id >> 5, nn = id & 31;
    S[r * 32 + nn] = abase[(size_t)r * NHID + nn];
  }

  const bool isFIR = (tid < 384);
  const int g   = tid / 96;          // tap group 0..3 (FIR threads)
  const int rem = tid - g * 96;
  const int q   = rem >> 5;          // t-quad 0..2
  const int n   = rem & 31;          // neuron
  double tap[20];
  __syncthreads();                   // TB + tile0 visible
  if (isFIR) {
#pragma unroll
    for (int j = 0; j < 20; ++j) tap[j] = TB[20 * g + j];
  }
  double refk[11];
#pragma unroll
  for (int j = 1; j <= 10; ++j) refk[j] = ref_tap(j);
  uint32_t smask = 0;

  for (int k = 0; k < NT5; ++k) {
    const int t0 = k * TT5;
    const int tv = (T_SIM - t0 < TT5) ? (T_SIM - t0) : TT5;
    const int t0n = t0 + TT5;
    const int tvn = (t0n >= T_SIM) ? 0 : ((T_SIM - t0n < TT5) ? (T_SIM - t0n) : TT5);
    if (isFIR) {
      // ---- prefetch 1 element of tile k+1 (completes under the FIR) ----
      double pf = 0.0;
      const int pr = tid >> 5, pn = tid & 31;
      const bool hasPf = (tid < tvn * 32);
      if (hasPf) pf = abase[(size_t)(t0n + pr) * NHID + pn];
      // ---- partial FIR: outputs tb..tb+3, taps 20g..20g+19 ----
      const int tb = t0 + q * 4;
      int slot = (tb - 20 * g - 19 + 1024) & (RING5 - 1);
      double a0 = 0, a1 = 0, a2 = 0, a3 = 0;
#pragma unroll
      for (int s = 0; s < 23; ++s) {
        const double v = S[slot * 32 + n];
        slot = (slot + 1) & (RING5 - 1);
        if (s <= 19)           a0 += tap[19 - s] * v;
        if (s >= 1 && s <= 20) a1 += tap[20 - s] * v;
        if (s >= 2 && s <= 21) a2 += tap[21 - s] * v;
        if (s >= 3)            a3 += tap[22 - s] * v;
      }
      double* Yk = Yp[k & 1][g];
      const int tl = q * 4;
      if (tl + 0 < tv) Yk[(tl + 0) * 32 + n] = a0;
      if (tl + 1 < tv) Yk[(tl + 1) * 32 + n] = a1;
      if (tl + 2 < tv) Yk[(tl + 2) * 32 + n] = a2;
      if (tl + 3 < tv) Yk[(tl + 3) * 32 + n] = a3;
      // ---- write prefetched row into ring (slots disjoint from window k) ----
      if (hasPf) S[((t0n + pr) & (RING5 - 1)) * 32 + pn] = pf;
    } else if (k > 0) {
      // ---- scan wave: refractory scan of tile k-1 (tv always 12 there) ----
      const int lane = tid - 384;
      if (lane < 32) {
        const int t0p = t0 - TT5;
        const double* Y0 = Yp[(k - 1) & 1][0];
        const double* Y1 = Yp[(k - 1) & 1][1];
        const double* Y2 = Yp[(k - 1) & 1][2];
        const double* Y3 = Yp[(k - 1) & 1][3];
        for (int gg = 0; gg < TT5; ++gg) {
          double u = (Y0[gg * 32 + lane] + Y1[gg * 32 + lane]) +
                     (Y2[gg * 32 + lane] + Y3[gg * 32 + lane]);
#pragma unroll
          for (int j = 10; j >= 1; --j)
            u += refk[j] * (double)((smask >> (j - 1)) & 1u);
          const bool sp = (u >= 10.0);
          smask = (smask << 1) | (sp ? 1u : 0u);
          const unsigned long long bm = __ballot(sp);
          if (lane == 0) sbase[(size_t)(t0p + gg) * 32] = (uint32_t)bm;
        }
      }
    }
    __syncthreads();
  }
  // ---- epilogue: scan last tile (t0p = 492, tv = 8) ----
  if (!isFIR) {
    const int lane = tid - 384;
    if (lane < 32) {
      const int t0p = (NT5 - 1) * TT5;
      const int tvp = T_SIM - t0p;
      const double* Y0 = Yp[(NT5 - 1) & 1][0];
      const double* Y1 = Yp[(NT5 - 1) & 1][1];
      const double* Y2 = Yp[(NT5 - 1) & 1][2];
      const double* Y3 = Yp[(NT5 - 1) & 1][3];
      for (int gg = 0; gg < tvp; ++gg) {
        double u = (Y0[gg * 32 + lane] + Y1[gg * 32 + lane]) +
                   (Y2[gg * 32 + lane] + Y3[gg * 32 + lane]);
#pragma unroll
        for (int j = 10; j >= 1; --j)
          u += refk[j] * (double)((smask >> (j - 1)) & 1u);
        const bool sp = (u >= 10.0);
        smask = (smask << 1) | (sp ? 1u : 0u);
        const unsigned long long bm = __ballot(sp);
        if (lane == 0) sbase[(size_t)(t0p + gg) * 32] = (uint32_t)bm;
      }
    }
  }
}

// ---------------------------------------------------------------------------
// K3: dense2 sparse gather from s1 u32 masks, W2 fp32 in LDS, f64 acc.
__global__ __launch_bounds__(256)
void k_dense2(const uint32_t* __restrict__ s1w,
              const float* __restrict__ W2, double* __restrict__ a2) {
  __shared__ float w2t[NHID * NOUT];  // 40 KB, [i][o]
  for (int k = threadIdx.x; k < NHID * NOUT; k += 256) {
    const int o = k >> 10, i = k & 1023;
    w2t[i * NOUT + o] = W2[k];
  }
  __syncthreads();
  const int col = blockIdx.x * 256 + threadIdx.x;  // 0..31999
  double acc[NOUT];
#pragma unroll
  for (int o = 0; o < NOUT; ++o) acc[o] = 0.0;
  const uint32_t* w = s1w + (size_t)col * 32;
  for (int wi = 0; wi < 32; ++wi) {
    uint32_t m = w[wi];
    const int ibase = wi * 32;
    while (m) {
      const int j = __ffs(m) - 1;
      m &= m - 1;
      const float* row = &w2t[(ibase + j) * NOUT];
#pragma unroll
      for (int o = 0; o < NOUT; ++o) acc[o] += (double)row[o];
    }
  }
  double* outp = a2 + (size_t)col * NOUT;
#pragma unroll
  for (int o = 0; o < NOUT; ++o) outp[o] = acc[o];
}

// ---------------------------------------------------------------------------
// K4: FUSED psp2 + spike2, one block per batch; whole [500][10] in LDS.
__global__ __launch_bounds__(256)
void k_l2(const double* __restrict__ a2, float* __restrict__ out) {
  __shared__ double S[T_SIM * NOUT];
  __shared__ double Y[T_SIM * NOUT];
  __shared__ double srm[KSRM];
  const int b = blockIdx.x, tid = threadIdx.x;
  if (tid < KSRM) srm[tid] = srm_tap(tid);
  for (int i = tid; i < T_SIM * NOUT; i += 256)
    S[i] = a2[(size_t)b * T_SIM * NOUT + i];
  __syncthreads();
  for (int i = tid; i < T_SIM * NOUT; i += 256) {
    const int t = i / 10, o = i - t * 10;
    const int kmax = (t < KSRM - 1) ? t : (KSRM - 1);
    double acc = 0.0;
    for (int k = 0; k <= kmax; ++k)
      acc += srm[k] * S[(t - k) * 10 + o];
    Y[i] = acc;
  }
  __syncthreads();
  if (tid < NOUT) {
    double refk[11];
#pragma unroll
    for (int j = 1; j <= 10; ++j) refk[j] = ref_tap(j);
    uint32_t smask = 0;
    float* op = out + ((size_t)b * NOUT + tid) * T_SIM;
    for (int t = 0; t < T_SIM; ++t) {
      double u = Y[t * 10 + tid];
#pragma unroll
      for (int j = 10; j >= 1; --j)
        u += refk[j] * (double)((smask >> (j - 1)) & 1u);
      const bool sp = (u >= 10.0);
      smask = (smask << 1) | (sp ? 1u : 0u);
      op[t] = sp ? 1.0f : 0.0f;
    }
  }
}

// ---------------------------------------------------------------------------
extern "C" void kernel_launch(void* const* d_in, const int* in_sizes, int n_in,
                              void* d_out, int out_size, void* d_ws, size_t ws_size,
                              hipStream_t stream) {
  const float* x  = (const float*)d_in[0];   // [64][1024][500]
  const float* W1 = (const float*)d_in[1];   // [1024][1024]
  const float* W2 = (const float*)d_in[2];   // [10][1024]
  float* out = (float*)d_out;                // [64][10][500]

  char* ws = (char*)d_ws;
  unsigned long long* bits1 = (unsigned long long*)(ws);   // 4,096,000
  float*  W1T = (float*) (ws + 4096000);                   // 4,194,304
  double* a1c = (double*)(ws + 8290304);                   // 131,072,000 (CHUNK=32)
  uint32_t* s1w = (uint32_t*)(ws + 139362304);             // 4,096,000
  double* a2  = (double*)(ws + 143458304);                 // 2,560,000
  // total ws use: 146,018,304 B

  hipLaunchKernelGGL(k_pack, dim3(NB, 16, 5), dim3(64), 0, stream, x, bits1);
  hipLaunchKernelGGL(k_transpose, dim3(16, 16), dim3(256), 0, stream, W1, W1T);

  for (int bc = 0; bc < NB; bc += CHUNK) {
    hipLaunchKernelGGL(k_dense1, dim3(250 * 4), dim3(512), 0, stream,
                       (const uint32_t*)bits1, W1T, a1c, bc * T_SIM);
    hipLaunchKernelGGL(k_ps1, dim3(32, CHUNK), dim3(448), 0, stream,
                       a1c, s1w, bc);
  }

  hipLaunchKernelGGL(k_dense2, dim3(125), dim3(256), 0, stream, s1w, W2, a2);
  hipLaunchKernelGGL(k_l2, dim3(NB), dim3(256), 0, stream, a2, out);
}